// Round 5
// baseline (95319.427 us; speedup 1.0000x reference)
//
#include <hip/hip_runtime.h>
#include <math.h>

// WaveRNN autoregressive sampler, persistent kernel, fp32.
// Round 5 restructure: TWO grid barriers per step (was 5).
//   P1  (192 WGs x 512 thr): hp = W_hh_r @ h + b_hh, 14 rows/WG, LDS weights,
//        store hp transposed hpg[b][r] for coalesced head reads.
//   HEAD (32 WGs, one per batch): coarse GRU -> FC1c -> FC2c -> argmax ->
//        fine GRU -> FC1f -> FC2f -> argmax, all LDS-synced, no grid barriers.
//        c_hid/f_hid/csamp/fsamp live in head LDS across all 1024 steps.
// Round-4 evidence: FETCH reduction gave zero time gain -> latency-bound on
// barrier count + sc1 exchange with 1 wave/SIMD. This cuts barriers 5->2,
// sc1 volume 52->16 MB/step, and doubles waves/CU.

#define HALFN  448
#define SIZEN  896
#define RTOT   2688
#define NB     32
#define TSTEPS 1024
#define NWG    224
#define NHEAD  32
#define NTHR   512
#define ROWS_P1 14            // 192 WGs * 14 = 2688 rows
#define CONDSTR (RTOT * TSTEPS)

// reordered row -> original row: chunks [cr,cu,ce,fr,fu,fe] <- orig {0,2,4,1,3,5}
__device__ __forceinline__ int orig_row(int r) {
  int c = r / HALFN, o = r - c * HALFN;
  int oc = (c < 3) ? (2 * c) : (2 * (c - 3) + 1);
  return oc * HALFN + o;
}

__device__ __forceinline__ float sigm(float x) { return 1.0f / (1.0f + expf(-x)); }

// Cross-XCD coherent access (served at the LLC; verified rounds 2-4).
__device__ __forceinline__ float gload(const float* p) {
  return __hip_atomic_load(const_cast<float*>(p), __ATOMIC_RELAXED, __HIP_MEMORY_SCOPE_AGENT);
}
__device__ __forceinline__ void gstore(float* p, float v) {
  __hip_atomic_store(p, v, __ATOMIC_RELAXED, __HIP_MEMORY_SCOPE_AGENT);
}

union __align__(16) SMem {
  struct {                       // P1 WGs (w >= 32)
    float whh[ROWS_P1][SIZEN];   // 50176 B
    float red[8][ROWS_P1][32];   // 14336 B (16 k-slices pair-combined by shfl)
    float bhh[ROWS_P1];
  } p1;
  struct {                       // head WGs (w < 32)
    float wcif[2688];            // wci flat [1344][2]
    float wfif[4032];            // wfi flat [1344][3]
    float bihl[2688];
    float bc1l[HALFN], bf1l[HALFN];
    float bc2l[256],  bf2l[256];
    float hp[RTOT];              // this batch's hp column
    float chid[HALFN], fhid[HALFN];  // persistent hidden state (all steps!)
    float h1[HALFN];
    float logit[256];
    float cs, fs;                // persistent sample state
    int   bcast;
  } hd;
};

// Fence-free grid barrier (rounds 2-4): drain own vmem, relaxed agent flag
// store, relaxed polling. No cache maintenance -> L2/LDS stay hot.
__device__ __forceinline__ void gridbar(unsigned* flags, unsigned ep, int& dead) {
  asm volatile("s_waitcnt vmcnt(0)" ::: "memory");
  __syncthreads();
  if (threadIdx.x == 0)
    __hip_atomic_store(&flags[blockIdx.x], ep, __ATOMIC_RELAXED, __HIP_MEMORY_SCOPE_AGENT);
  if (!dead) {
    int iters = 0;
    for (;;) {
      int ok = 1;
      if (threadIdx.x < NWG) {
        unsigned v = __hip_atomic_load(&flags[threadIdx.x], __ATOMIC_RELAXED, __HIP_MEMORY_SCOPE_AGENT);
        ok = (v >= ep) ? 1 : 0;
      }
      if (__syncthreads_and(ok)) break;
      if (++iters > (1 << 20)) { dead = 1; break; }  // anti-hang valve
      __builtin_amdgcn_s_sleep(2);
    }
  } else {
    __syncthreads();
  }
}

// ws layout: hidg [896*32] (hidg[j*32+b]) | hpg [32*2688] (hpg[b*2688+r]) | flags
extern "C" __global__ void wavernn_init(float* ws) {
  int i = blockIdx.x * blockDim.x + threadIdx.x;
  int stride = gridDim.x * blockDim.x;
  for (int k = i; k < SIZEN * NB; k += stride) ws[k] = 0.0f;   // hidden = 0
  if (i < 256) ((unsigned*)(ws + 114688))[i] = 0u;             // barrier flags
}

extern "C" __global__ void __launch_bounds__(NTHR)
wavernn_persist(const float* __restrict__ cond,
                const float* __restrict__ wci, const float* __restrict__ wfi,
                const float* __restrict__ whh, const float* __restrict__ bih,
                const float* __restrict__ bhh,
                const float* __restrict__ wc1, const float* __restrict__ bc1,
                const float* __restrict__ wc2, const float* __restrict__ bc2,
                const float* __restrict__ wf1, const float* __restrict__ bf1,
                const float* __restrict__ wf2, const float* __restrict__ bf2,
                float* __restrict__ out, float* ws) {
  __shared__ SMem sm;

  float* hidg = ws;                       // [896][32]
  float* hpg  = ws + 28672;               // [32][2688]
  unsigned* flags = (unsigned*)(ws + 114688);

  const int w = blockIdx.x, tid = threadIdx.x;
  const bool isHead = (w < NHEAD);
  const int p = w - NHEAD;                // P1 WG index 0..191
  unsigned ep = 0;
  int dead = 0;

  // ---------- one-time LDS staging ----------
  if (isHead) {
    for (int i = tid; i < 2688; i += NTHR) { sm.hd.wcif[i] = wci[i]; sm.hd.bihl[i] = bih[i]; }
    for (int i = tid; i < 4032; i += NTHR) sm.hd.wfif[i] = wfi[i];
    if (tid < HALFN) {
      sm.hd.bc1l[tid] = bc1[tid]; sm.hd.bf1l[tid] = bf1[tid];
      sm.hd.chid[tid] = 0.0f;     sm.hd.fhid[tid] = 0.0f;
    }
    if (tid < 256) { sm.hd.bc2l[tid] = bc2[tid]; sm.hd.bf2l[tid] = bf2[tid]; }
    if (tid == 0) { sm.hd.cs = 128.0f; sm.hd.fs = 0.0f; }
  } else {
#pragma unroll
    for (int rr = 0; rr < ROWS_P1; rr++) {
      const float* src = whh + (size_t)orig_row(p * ROWS_P1 + rr) * SIZEN;
      for (int k = tid * 4; k < SIZEN; k += NTHR * 4)
        *(float4*)&sm.p1.whh[rr][k] = *(const float4*)&src[k];
    }
    if (tid < ROWS_P1) sm.p1.bhh[tid] = bhh[orig_row(p * ROWS_P1 + tid)];
  }
  __syncthreads();

  for (int t = 0; t < TSTEPS; ++t) {
    // ================= P1: hp GEMM =================
    if (!isHead) {
      const int b = tid & 31, ks = tid >> 5;    // ks in [0,16), 56-wide k-slice
      const int k0 = ks * 56;
      float acc[ROWS_P1];
#pragma unroll
      for (int rr = 0; rr < ROWS_P1; rr++) acc[rr] = 0.0f;
      const float* hcol = hidg + b;
#pragma unroll 2
      for (int k = k0; k < k0 + 56; k += 4) {
        float h0 = gload(&hcol[(k + 0) * 32]), h1v = gload(&hcol[(k + 1) * 32]);
        float h2 = gload(&hcol[(k + 2) * 32]), h3  = gload(&hcol[(k + 3) * 32]);
#pragma unroll
        for (int rr = 0; rr < ROWS_P1; rr++) {
          const float4 wv = *(const float4*)&sm.p1.whh[rr][k];
          acc[rr] = fmaf(wv.x, h0, fmaf(wv.y, h1v, fmaf(wv.z, h2, fmaf(wv.w, h3, acc[rr]))));
        }
      }
      // combine even/odd k-slices within the wave (lanes differ by 32)
#pragma unroll
      for (int rr = 0; rr < ROWS_P1; rr++) acc[rr] += __shfl_xor(acc[rr], 32);
      __syncthreads();
      if ((tid & 32) == 0) {
        int slice = ks >> 1;   // 0..7
#pragma unroll
        for (int rr = 0; rr < ROWS_P1; rr++) sm.p1.red[slice][rr][b] = acc[rr];
      }
      __syncthreads();
      if (tid < ROWS_P1 * 32) {
        int rr = tid >> 5, bb = tid & 31;
        float s = sm.p1.bhh[rr];
#pragma unroll
        for (int kk = 0; kk < 8; kk++) s += sm.p1.red[kk][rr][bb];
        gstore(&hpg[(size_t)bb * RTOT + p * ROWS_P1 + rr], s);
      }
    }
    gridbar(flags, ++ep, dead);   // ---- bar1: hp ready ----

    // ================= HEAD: everything per batch =================
    if (isHead) {
      const int b2 = w;
      // 1. hp column -> LDS (coalesced: consecutive lanes, consecutive r)
      for (int i = tid; i < RTOT; i += NTHR)
        sm.hd.hp[i] = gload(&hpg[(size_t)b2 * RTOT + i]);
      __syncthreads();
      const float cs = sm.hd.cs, fs = sm.hd.fs;
      const float sc = cs * (2.0f / 255.0f) - 1.0f;
      const float sf = fs * (2.0f / 255.0f) - 1.0f;
      const float* condb = cond + (size_t)b2 * CONDSTR + t;

      // 2. coarse GRU (448 threads, one j each)
      if (tid < HALFN) {
        int j = tid;
        float ipr = sm.hd.wcif[j * 2]            * sc + sm.hd.wcif[j * 2 + 1]            * sf
                  + condb[(size_t)j * TSTEPS]            + sm.hd.bihl[j];
        float ipu = sm.hd.wcif[(HALFN + j) * 2]  * sc + sm.hd.wcif[(HALFN + j) * 2 + 1]  * sf
                  + condb[(size_t)(SIZEN + j) * TSTEPS]  + sm.hd.bihl[SIZEN + j];
        float ipe = sm.hd.wcif[(SIZEN + j) * 2]  * sc + sm.hd.wcif[(SIZEN + j) * 2 + 1]  * sf
                  + condb[(size_t)(1792 + j) * TSTEPS]   + sm.hd.bihl[1792 + j];
        float r = sigm(sm.hd.hp[j] + ipr);
        float u = sigm(sm.hd.hp[HALFN + j] + ipu);
        float e = tanhf(fmaf(r, sm.hd.hp[SIZEN + j], ipe));
        float hnew = u * sm.hd.chid[j] + (1.0f - u) * e;
        sm.hd.chid[j] = hnew;
        gstore(&hidg[j * 32 + b2], hnew);       // publish for next P1
      }
      __syncthreads();

      // 3. FC1 coarse: h1 = relu(wc1 @ chid + bc1)
      if (tid < HALFN) {
        const float4* wr = (const float4*)(wc1 + (size_t)tid * HALFN);
        float a = sm.hd.bc1l[tid];
#pragma unroll 4
        for (int i = 0; i < HALFN / 4; i++) {
          float4 v = wr[i];
          a = fmaf(v.x, sm.hd.chid[4 * i],     fmaf(v.y, sm.hd.chid[4 * i + 1],
              fmaf(v.z, sm.hd.chid[4 * i + 2], fmaf(v.w, sm.hd.chid[4 * i + 3], a))));
        }
        sm.hd.h1[tid] = fmaxf(a, 0.0f);
      }
      __syncthreads();

      // 4. FC2 coarse (row = tid>>1, two k-halves) + argmax
      {
        int row = tid >> 1, kh = tid & 1;
        const float4* wr = (const float4*)(wc2 + (size_t)row * HALFN) + kh * 56;
        const float*  hh = sm.hd.h1 + kh * 224;
        float a = 0.0f;
#pragma unroll 4
        for (int i = 0; i < 56; i++) {
          float4 v = wr[i];
          a = fmaf(v.x, hh[4 * i],     fmaf(v.y, hh[4 * i + 1],
              fmaf(v.z, hh[4 * i + 2], fmaf(v.w, hh[4 * i + 3], a))));
        }
        a += __shfl_xor(a, 1);
        if (kh == 0) sm.hd.logit[row] = a + sm.hd.bc2l[row];
      }
      __syncthreads();
      if (tid < 64) {
        float v = -3.4e38f; int vi = 0;
#pragma unroll
        for (int q = 0; q < 4; q++) {
          int r = tid * 4 + q; float x = sm.hd.logit[r];
          if (x > v) { v = x; vi = r; }
        }
#pragma unroll
        for (int off = 1; off < 64; off <<= 1) {
          float ov = __shfl_xor(v, off); int oi = __shfl_xor(vi, off);
          if (ov > v || (ov == v && oi < vi)) { v = ov; vi = oi; }
        }
        if (tid == 0) sm.hd.bcast = vi;
      }
      __syncthreads();
      const int nc = sm.hd.bcast;
      const float snc = nc * (2.0f / 255.0f) - 1.0f;

      // 5. fine GRU
      if (tid < HALFN) {
        int j = tid;
        float ipr = sm.hd.wfif[j * 3] * sc + sm.hd.wfif[j * 3 + 1] * sf + sm.hd.wfif[j * 3 + 2] * snc
                  + condb[(size_t)(HALFN + j) * TSTEPS] + sm.hd.bihl[HALFN + j];
        float ipu = sm.hd.wfif[(HALFN + j) * 3] * sc + sm.hd.wfif[(HALFN + j) * 3 + 1] * sf + sm.hd.wfif[(HALFN + j) * 3 + 2] * snc
                  + condb[(size_t)(1344 + j) * TSTEPS] + sm.hd.bihl[1344 + j];
        float ipe = sm.hd.wfif[(SIZEN + j) * 3] * sc + sm.hd.wfif[(SIZEN + j) * 3 + 1] * sf + sm.hd.wfif[(SIZEN + j) * 3 + 2] * snc
                  + condb[(size_t)(2240 + j) * TSTEPS] + sm.hd.bihl[2240 + j];
        float r = sigm(sm.hd.hp[1344 + j] + ipr);
        float u = sigm(sm.hd.hp[1792 + j] + ipu);
        float e = tanhf(fmaf(r, sm.hd.hp[2240 + j], ipe));
        float hnew = u * sm.hd.fhid[j] + (1.0f - u) * e;
        sm.hd.fhid[j] = hnew;
        gstore(&hidg[(HALFN + j) * 32 + b2], hnew);
      }
      __syncthreads();

      // 6. FC1 fine
      if (tid < HALFN) {
        const float4* wr = (const float4*)(wf1 + (size_t)tid * HALFN);
        float a = sm.hd.bf1l[tid];
#pragma unroll 4
        for (int i = 0; i < HALFN / 4; i++) {
          float4 v = wr[i];
          a = fmaf(v.x, sm.hd.fhid[4 * i],     fmaf(v.y, sm.hd.fhid[4 * i + 1],
              fmaf(v.z, sm.hd.fhid[4 * i + 2], fmaf(v.w, sm.hd.fhid[4 * i + 3], a))));
        }
        sm.hd.h1[tid] = fmaxf(a, 0.0f);
      }
      __syncthreads();

      // 7. FC2 fine + argmax
      {
        int row = tid >> 1, kh = tid & 1;
        const float4* wr = (const float4*)(wf2 + (size_t)row * HALFN) + kh * 56;
        const float*  hh = sm.hd.h1 + kh * 224;
        float a = 0.0f;
#pragma unroll 4
        for (int i = 0; i < 56; i++) {
          float4 v = wr[i];
          a = fmaf(v.x, hh[4 * i],     fmaf(v.y, hh[4 * i + 1],
              fmaf(v.z, hh[4 * i + 2], fmaf(v.w, hh[4 * i + 3], a))));
        }
        a += __shfl_xor(a, 1);
        if (kh == 0) sm.hd.logit[row] = a + sm.hd.bf2l[row];
      }
      __syncthreads();
      if (tid < 64) {
        float v = -3.4e38f; int vi = 0;
#pragma unroll
        for (int q = 0; q < 4; q++) {
          int r = tid * 4 + q; float x = sm.hd.logit[r];
          if (x > v) { v = x; vi = r; }
        }
#pragma unroll
        for (int off = 1; off < 64; off <<= 1) {
          float ov = __shfl_xor(v, off); int oi = __shfl_xor(vi, off);
          if (ov > v || (ov == v && oi < vi)) { v = ov; vi = oi; }
        }
        if (tid == 0) sm.hd.bcast = vi;
      }
      __syncthreads();

      // 8. sample writeback + persistent state update
      if (tid == 0) {
        int nf = sm.hd.bcast;
        out[(size_t)b2 * TSTEPS + t]         = (float)nc;
        out[32768 + (size_t)b2 * TSTEPS + t] = (float)nf;
        sm.hd.cs = (float)nc;
        sm.hd.fs = (float)nf;
      }
      // (cs/fs re-read next step only after gridbar's __syncthreads)
    }
    gridbar(flags, ++ep, dead);   // ---- bar2: hidden published ----
  }

  // final hidden: [c_hid; f_hid] (896 x 32) straight from head LDS
  if (isHead && tid < HALFN) {
    out[65536 + (size_t)tid * 32 + w]           = sm.hd.chid[tid];
    out[65536 + (size_t)(HALFN + tid) * 32 + w] = sm.hd.fhid[tid];
  }
}

extern "C" void kernel_launch(void* const* d_in, const int* in_sizes, int n_in,
                              void* d_out, int out_size, void* d_ws, size_t ws_size,
                              hipStream_t stream) {
  const float* cond = (const float*)d_in[0];
  const float* wci  = (const float*)d_in[1];
  const float* wfi  = (const float*)d_in[2];
  const float* whh  = (const float*)d_in[3];
  const float* bih  = (const float*)d_in[4];
  const float* bhh  = (const float*)d_in[5];
  const float* wc1  = (const float*)d_in[6];
  const float* bc1  = (const float*)d_in[7];
  const float* wc2  = (const float*)d_in[8];
  const float* bc2  = (const float*)d_in[9];
  const float* wf1  = (const float*)d_in[10];
  const float* bf1  = (const float*)d_in[11];
  const float* wf2  = (const float*)d_in[12];
  const float* bf2  = (const float*)d_in[13];
  float* out = (float*)d_out;
  float* ws  = (float*)d_ws;

  hipLaunchKernelGGL(wavernn_init, dim3(64), dim3(256), 0, stream, ws);
  hipLaunchKernelGGL(wavernn_persist, dim3(NWG), dim3(NTHR), 0, stream,
                     cond, wci, wfi, whh, bih, bhh,
                     wc1, bc1, wc2, bc2, wf1, bf1, wf2, bf2, out, ws);
}

// Round 6
// 42132.166 us; speedup vs baseline: 2.2624x; 2.2624x over previous
//
#include <hip/hip_runtime.h>
#include <math.h>

// WaveRNN autoregressive sampler, persistent kernel, fp32. Round 6:
// ALL weights LDS-resident; every matmul row-split; 6 grid barriers/step.
// Round-5 lesson: any weight bytes read from global per step miss L2 and
// convert 1:1 into step time (11 MB/step -> 93 us/step). Round 3-5 lesson:
// relaxed-agent atomic state exchange is mostly L2-served (cheap).
// Phases: P1 GEMM+nf-finalize+cGRU | P2 FC1c | P3 FC2c+partial-argmax |
//         P4 head: nc + fGRU | P5 FC1f | P6 FC2f+partial-argmax.
// Weight map per WG: whh rows {c*448+2w,2w+1}, wc1/wf1 rows {2w,2w+1},
// wc2/wf2 rows {8w..8w+7} (w<32). Hidden double-buffered in ws.

#define HALFN  448
#define SIZEN  896
#define RTOT   2688
#define NB     32
#define TSTEPS 1024
#define NWG    224
#define NTHR   512
#define CONDSTR (RTOT * TSTEPS)

// ws float offsets
#define OFF_HID0  0         // [896*32] h buffer A   (hid[j*32+b])
#define OFF_HID1  28672     // [896*32] h buffer B
#define OFF_HPF   57344     // [1344*32] fine-gate hp rows
#define OFF_H1G   100352    // [448*32] FC1 output (coarse then fine)
#define OFF_CS    114688    // [32] coarse sample (float)
#define OFF_CANDC 114720    // [32*32*2] FC2c candidates (val,idx)
#define OFF_CANDF 116768    // [32*32*2] FC2f candidates
#define OFF_FLAGS 118816    // [256] barrier flags (uint)

__device__ __forceinline__ int orig_row(int r) {   // reordered -> original
  int c = r / HALFN, o = r - c * HALFN;
  int oc = (c < 3) ? (2 * c) : (2 * (c - 3) + 1);
  return oc * HALFN + o;
}
__device__ __forceinline__ float sigm(float x) { return 1.0f / (1.0f + expf(-x)); }

__device__ __forceinline__ float gload(const float* p) {
  return __hip_atomic_load(const_cast<float*>(p), __ATOMIC_RELAXED, __HIP_MEMORY_SCOPE_AGENT);
}
__device__ __forceinline__ void gstore(float* p, float v) {
  __hip_atomic_store(p, v, __ATOMIC_RELAXED, __HIP_MEMORY_SCOPE_AGENT);
}

struct __align__(16) SM {
  float whh[12][SIZEN];     // 43008
  float wc1l[2][HALFN];     // 3584
  float wf1l[2][HALFN];     // 3584
  float wc2l[8][HALFN];     // 14336 (w<32)
  float wf2l[8][HALFN];     // 14336 (w<32)
  float red[8][12][32];     // 12288 partial sums
  float hps[6][32];         // coarse hp (r0,r1,u0,u1,e0,e1 rows x batch)
  float chid[2][32];        // persistent c_hid slice (j=2w,2w+1)
  float fhid[HALFN];        // persistent f_hid (head WGs)
  float scv[32], sfv[32], nfv[32];
  float logit8[8][32];
  float redmv[8][32]; float redmi[8][32];
  float bhh_l[12];
  int   bcast;
};

__device__ __forceinline__ void gridbar(unsigned* flags, unsigned ep, int& dead) {
  asm volatile("s_waitcnt vmcnt(0)" ::: "memory");
  __syncthreads();
  if (threadIdx.x == 0)
    __hip_atomic_store(&flags[blockIdx.x], ep, __ATOMIC_RELAXED, __HIP_MEMORY_SCOPE_AGENT);
  if (!dead) {
    int iters = 0;
    for (;;) {
      int ok = 1;
      if (threadIdx.x < NWG) {
        unsigned v = __hip_atomic_load(&flags[threadIdx.x], __ATOMIC_RELAXED, __HIP_MEMORY_SCOPE_AGENT);
        ok = (v >= ep) ? 1 : 0;
      }
      if (__syncthreads_and(ok)) break;
      if (++iters > (1 << 20)) { dead = 1; break; }
      __builtin_amdgcn_s_sleep(1);
    }
  } else {
    __syncthreads();
  }
}

extern "C" __global__ void wavernn_init(float* ws) {
  int i = blockIdx.x * blockDim.x + threadIdx.x;
  int stride = gridDim.x * blockDim.x;
  for (int k = i; k < 2 * SIZEN * NB; k += stride) ws[k] = 0.0f;       // both h buffers
  if (i < NB) ws[OFF_CS + i] = 128.0f;
  // candf init: batch b picks idx 0 at t=0 (fine init = 0)
  for (int k = i; k < 2048; k += stride) ws[OFF_CANDF + k] = 0.0f;
  if (i < NB * 32) {
    int w = i >> 5, b = i & 31;
    ws[OFF_CANDF + (w * 32 + b) * 2] = (w == 0) ? 1.0f : -3.4e38f;
  }
  if (i < 256) ((unsigned*)(ws + OFF_FLAGS))[i] = 0u;
}

extern "C" __global__ void __launch_bounds__(NTHR)
wavernn_persist(const float* __restrict__ cond,
                const float* __restrict__ wci, const float* __restrict__ wfi,
                const float* __restrict__ whh, const float* __restrict__ bih,
                const float* __restrict__ bhh,
                const float* __restrict__ wc1, const float* __restrict__ bc1,
                const float* __restrict__ wc2, const float* __restrict__ bc2,
                const float* __restrict__ wf1, const float* __restrict__ bf1,
                const float* __restrict__ wf2, const float* __restrict__ bf2,
                float* __restrict__ out, float* ws) {
  __shared__ SM sm;

  float* hid0 = ws + OFF_HID0;
  float* hid1 = ws + OFF_HID1;
  float* hpf  = ws + OFF_HPF;
  float* h1g  = ws + OFF_H1G;
  float* csampv = ws + OFF_CS;
  float* candc = ws + OFF_CANDC;
  float* candf = ws + OFF_CANDF;
  unsigned* flags = (unsigned*)(ws + OFF_FLAGS);

  const int w = blockIdx.x, tid = threadIdx.x;
  const int b = tid & 31, ks = tid >> 5;     // 16 k-slices x 32 batch
  const bool isHead = (w < NB);
  unsigned ep = 0;
  int dead = 0;

  // ---------- one-time LDS weight staging ----------
#pragma unroll
  for (int rr = 0; rr < 12; rr++) {
    int R = (rr >> 1) * HALFN + 2 * w + (rr & 1);
    const float* src = whh + (size_t)orig_row(R) * SIZEN;
    for (int k = tid * 4; k < SIZEN; k += NTHR * 4)
      *(float4*)&sm.whh[rr][k] = *(const float4*)&src[k];
  }
  if (tid < 12) sm.bhh_l[tid] = bhh[orig_row((tid >> 1) * HALFN + 2 * w + (tid & 1))];
  for (int k = tid * 4; k < HALFN; k += NTHR * 4) {
    *(float4*)&sm.wc1l[0][k] = *(const float4*)&wc1[(size_t)(2 * w) * HALFN + k];
    *(float4*)&sm.wc1l[1][k] = *(const float4*)&wc1[(size_t)(2 * w + 1) * HALFN + k];
    *(float4*)&sm.wf1l[0][k] = *(const float4*)&wf1[(size_t)(2 * w) * HALFN + k];
    *(float4*)&sm.wf1l[1][k] = *(const float4*)&wf1[(size_t)(2 * w + 1) * HALFN + k];
  }
  if (isHead) {
#pragma unroll
    for (int rr = 0; rr < 8; rr++) {
      for (int k = tid * 4; k < HALFN; k += NTHR * 4) {
        *(float4*)&sm.wc2l[rr][k] = *(const float4*)&wc2[(size_t)(w * 8 + rr) * HALFN + k];
        *(float4*)&sm.wf2l[rr][k] = *(const float4*)&wf2[(size_t)(w * 8 + rr) * HALFN + k];
      }
    }
    if (tid < HALFN) sm.fhid[tid] = 0.0f;
  }
  if (tid < 64) sm.chid[tid >> 5][tid & 31] = 0.0f;
  __syncthreads();

  for (int t = 0; t < TSTEPS; ++t) {
    const float* hprev = (t & 1) ? hid0 : hid1;   // h(t-1)
    float*       hcur  = (t & 1) ? hid1 : hid0;   // h(t)

    // ========== P1: nf finalize + hp GEMM + coarse GRU ==========
    {
      // (a) reduce candf -> nf(t-1), scv/sfv for all batches
      if (tid < 256) {
        int bb = tid & 31, g = tid >> 5;          // g scans w=4g..4g+3
        float bv = -3.4e38f; float bi = 2.14e9f;
        for (int ww = g * 4; ww < g * 4 + 4; ++ww) {
          float cv = gload(&candf[(ww * 32 + bb) * 2]);
          float ci = gload(&candf[(ww * 32 + bb) * 2 + 1]);
          if (cv > bv || (cv == bv && ci < bi)) { bv = cv; bi = ci; }
        }
        sm.redmv[g][bb] = bv; sm.redmi[g][bb] = bi;
      }
      if (tid >= 256 && tid < 288) {
        int bb = tid - 256;
        sm.scv[bb] = gload(&csampv[bb]) * (2.0f / 255.0f) - 1.0f;
      }
      __syncthreads();
      if (tid < 32) {
        float bv = -3.4e38f; float bi = 2.14e9f;
#pragma unroll
        for (int g = 0; g < 8; g++) {
          float v = sm.redmv[g][tid], i = sm.redmi[g][tid];
          if (v > bv || (v == bv && i < bi)) { bv = v; bi = i; }
        }
        sm.nfv[tid] = bi;
        sm.sfv[tid] = bi * (2.0f / 255.0f) - 1.0f;
      }
      __syncthreads();
      if (isHead && tid == 0 && t > 0)
        out[32768 + (size_t)w * TSTEPS + (t - 1)] = sm.nfv[w];

      // (b) GEMM: 12 rows, k-slice 56 per ks
      float acc[12];
#pragma unroll
      for (int rr = 0; rr < 12; rr++) acc[rr] = 0.0f;
      const int k0 = ks * 56;
      const float* hcol = hprev + b;
#pragma unroll 2
      for (int k = k0; k < k0 + 56; k += 4) {
        float h0 = gload(&hcol[(k + 0) * 32]), h1v = gload(&hcol[(k + 1) * 32]);
        float h2 = gload(&hcol[(k + 2) * 32]), h3  = gload(&hcol[(k + 3) * 32]);
#pragma unroll
        for (int rr = 0; rr < 12; rr++) {
          const float4 wv = *(const float4*)&sm.whh[rr][k];
          acc[rr] = fmaf(wv.x, h0, fmaf(wv.y, h1v, fmaf(wv.z, h2, fmaf(wv.w, h3, acc[rr]))));
        }
      }
#pragma unroll
      for (int rr = 0; rr < 12; rr++) acc[rr] += __shfl_xor(acc[rr], 32);
      __syncthreads();
      if ((tid & 32) == 0) {
        int slot = ks >> 1;
#pragma unroll
        for (int rr = 0; rr < 12; rr++) sm.red[slot][rr][b] = acc[rr];
      }
      __syncthreads();
      if (tid < 384) {
        int rr = tid >> 5, bb = tid & 31;
        float s = sm.bhh_l[rr];
#pragma unroll
        for (int kk = 0; kk < 8; kk++) s += sm.red[kk][rr][bb];
        int chunk = rr >> 1, q = rr & 1;
        if (chunk < 3) sm.hps[rr][bb] = s;
        else gstore(&hpf[(size_t)((chunk - 3) * HALFN + 2 * w + q) * 32 + bb], s);
      }
      __syncthreads();

      // (c) coarse GRU for j = 2w, 2w+1 (hp rows are WG-local)
      if (tid < 64) {
        int q = tid >> 5, bb = tid & 31;
        int j = 2 * w + q;
        float sc = sm.scv[bb], sf = sm.sfv[bb];
        float ipr = wci[j * 2] * sc + wci[j * 2 + 1] * sf
                  + cond[(size_t)bb * CONDSTR + (size_t)j * TSTEPS + t] + bih[j];
        float ipu = wci[(HALFN + j) * 2] * sc + wci[(HALFN + j) * 2 + 1] * sf
                  + cond[(size_t)bb * CONDSTR + (size_t)(SIZEN + j) * TSTEPS + t] + bih[SIZEN + j];
        float ipe = wci[(SIZEN + j) * 2] * sc + wci[(SIZEN + j) * 2 + 1] * sf
                  + cond[(size_t)bb * CONDSTR + (size_t)(1792 + j) * TSTEPS + t] + bih[1792 + j];
        float r = sigm(sm.hps[0 + q][bb] + ipr);
        float u = sigm(sm.hps[2 + q][bb] + ipu);
        float e = tanhf(fmaf(r, sm.hps[4 + q][bb], ipe));
        float hnew = u * sm.chid[q][bb] + (1.0f - u) * e;
        sm.chid[q][bb] = hnew;
        gstore(&hcur[(size_t)j * 32 + bb], hnew);
      }
    }
    gridbar(flags, ++ep, dead);

    // ========== P2: FC1 coarse (rows 2w,2w+1) ==========
    {
      const int k0 = ks * 28;
      float a0 = 0.0f, a1 = 0.0f;
      const float* hcc = hcur + b;
#pragma unroll
      for (int k = k0; k < k0 + 28; k += 4) {
        float h0 = gload(&hcc[(k + 0) * 32]), h1v = gload(&hcc[(k + 1) * 32]);
        float h2 = gload(&hcc[(k + 2) * 32]), h3  = gload(&hcc[(k + 3) * 32]);
        float4 v0 = *(const float4*)&sm.wc1l[0][k];
        a0 = fmaf(v0.x, h0, fmaf(v0.y, h1v, fmaf(v0.z, h2, fmaf(v0.w, h3, a0))));
        float4 v1 = *(const float4*)&sm.wc1l[1][k];
        a1 = fmaf(v1.x, h0, fmaf(v1.y, h1v, fmaf(v1.z, h2, fmaf(v1.w, h3, a1))));
      }
      a0 += __shfl_xor(a0, 32); a1 += __shfl_xor(a1, 32);
      __syncthreads();
      if ((tid & 32) == 0) { sm.red[ks >> 1][0][b] = a0; sm.red[ks >> 1][1][b] = a1; }
      __syncthreads();
      if (tid < 64) {
        int rr = tid >> 5, bb = tid & 31;
        float s = bc1[2 * w + rr];
#pragma unroll
        for (int kk = 0; kk < 8; kk++) s += sm.red[kk][rr][bb];
        gstore(&h1g[(size_t)(2 * w + rr) * 32 + bb], fmaxf(s, 0.0f));
      }
    }
    gridbar(flags, ++ep, dead);

    // ========== P3: FC2 coarse row-split + partial argmax (w<32) ==========
    if (isHead) {
      const int k0 = ks * 28;
      float acc[8];
#pragma unroll
      for (int rr = 0; rr < 8; rr++) acc[rr] = 0.0f;
      const float* hh = h1g + b;
#pragma unroll
      for (int k = k0; k < k0 + 28; k += 4) {
        float h0 = gload(&hh[(k + 0) * 32]), h1v = gload(&hh[(k + 1) * 32]);
        float h2 = gload(&hh[(k + 2) * 32]), h3  = gload(&hh[(k + 3) * 32]);
#pragma unroll
        for (int rr = 0; rr < 8; rr++) {
          const float4 wv = *(const float4*)&sm.wc2l[rr][k];
          acc[rr] = fmaf(wv.x, h0, fmaf(wv.y, h1v, fmaf(wv.z, h2, fmaf(wv.w, h3, acc[rr]))));
        }
      }
#pragma unroll
      for (int rr = 0; rr < 8; rr++) acc[rr] += __shfl_xor(acc[rr], 32);
      __syncthreads();
      if ((tid & 32) == 0) {
        int slot = ks >> 1;
#pragma unroll
        for (int rr = 0; rr < 8; rr++) sm.red[slot][rr][b] = acc[rr];
      }
      __syncthreads();
      if (tid < 256) {
        int rr = tid >> 5, bb = tid & 31;
        float s = bc2[w * 8 + rr];
#pragma unroll
        for (int kk = 0; kk < 8; kk++) s += sm.red[kk][rr][bb];
        sm.logit8[rr][bb] = s;
      }
      __syncthreads();
      if (tid < 32) {
        float bv = sm.logit8[0][tid]; int bi = 0;
#pragma unroll
        for (int rr = 1; rr < 8; rr++) {
          float x = sm.logit8[rr][tid];
          if (x > bv) { bv = x; bi = rr; }
        }
        gstore(&candc[(w * 32 + tid) * 2], bv);
        gstore(&candc[(w * 32 + tid) * 2 + 1], (float)(w * 8 + bi));
      }
    }
    gridbar(flags, ++ep, dead);

    // ========== P4: head per batch: nc + fine GRU ==========
    if (isHead) {
      const int b2 = w;
      float v = -3.4e38f; float vi = 2.14e9f;
      if (tid < 32) {
        v  = gload(&candc[(tid * 32 + b2) * 2]);
        vi = gload(&candc[(tid * 32 + b2) * 2 + 1]);
      }
      if (tid < 64) {
#pragma unroll
        for (int off = 16; off >= 1; off >>= 1) {
          float ov = __shfl_xor(v, off); float oi = __shfl_xor(vi, off);
          if (ov > v || (ov == v && oi < vi)) { v = ov; vi = oi; }
        }
        if (tid == 0) sm.bcast = (int)vi;
      }
      __syncthreads();
      const int nc = sm.bcast;
      const float snc = nc * (2.0f / 255.0f) - 1.0f;
      const float sc = sm.scv[b2], sf = sm.sfv[b2];
      if (tid < HALFN) {
        int j = tid;
        float ipr = wfi[j * 3] * sc + wfi[j * 3 + 1] * sf + wfi[j * 3 + 2] * snc
                  + cond[(size_t)b2 * CONDSTR + (size_t)(HALFN + j) * TSTEPS + t] + bih[HALFN + j];
        float ipu = wfi[(HALFN + j) * 3] * sc + wfi[(HALFN + j) * 3 + 1] * sf + wfi[(HALFN + j) * 3 + 2] * snc
                  + cond[(size_t)b2 * CONDSTR + (size_t)(1344 + j) * TSTEPS + t] + bih[1344 + j];
        float ipe = wfi[(SIZEN + j) * 3] * sc + wfi[(SIZEN + j) * 3 + 1] * sf + wfi[(SIZEN + j) * 3 + 2] * snc
                  + cond[(size_t)b2 * CONDSTR + (size_t)(2240 + j) * TSTEPS + t] + bih[2240 + j];
        float r = sigm(gload(&hpf[(size_t)j * 32 + b2]) + ipr);
        float u = sigm(gload(&hpf[(size_t)(HALFN + j) * 32 + b2]) + ipu);
        float e = tanhf(fmaf(r, gload(&hpf[(size_t)(SIZEN + j) * 32 + b2]), ipe));
        float hnew = u * sm.fhid[j] + (1.0f - u) * e;
        sm.fhid[j] = hnew;
        gstore(&hcur[(size_t)(HALFN + j) * 32 + b2], hnew);
      }
      if (tid == 0) {
        out[(size_t)b2 * TSTEPS + t] = (float)nc;
        gstore(&csampv[b2], (float)nc);
      }
    }
    gridbar(flags, ++ep, dead);

    // ========== P5: FC1 fine (rows 2w,2w+1) ==========
    {
      const int k0 = ks * 28;
      float a0 = 0.0f, a1 = 0.0f;
      const float* hff = hcur + HALFN * 32 + b;
#pragma unroll
      for (int k = k0; k < k0 + 28; k += 4) {
        float h0 = gload(&hff[(k + 0) * 32]), h1v = gload(&hff[(k + 1) * 32]);
        float h2 = gload(&hff[(k + 2) * 32]), h3  = gload(&hff[(k + 3) * 32]);
        float4 v0 = *(const float4*)&sm.wf1l[0][k];
        a0 = fmaf(v0.x, h0, fmaf(v0.y, h1v, fmaf(v0.z, h2, fmaf(v0.w, h3, a0))));
        float4 v1 = *(const float4*)&sm.wf1l[1][k];
        a1 = fmaf(v1.x, h0, fmaf(v1.y, h1v, fmaf(v1.z, h2, fmaf(v1.w, h3, a1))));
      }
      a0 += __shfl_xor(a0, 32); a1 += __shfl_xor(a1, 32);
      __syncthreads();
      if ((tid & 32) == 0) { sm.red[ks >> 1][0][b] = a0; sm.red[ks >> 1][1][b] = a1; }
      __syncthreads();
      if (tid < 64) {
        int rr = tid >> 5, bb = tid & 31;
        float s = bf1[2 * w + rr];
#pragma unroll
        for (int kk = 0; kk < 8; kk++) s += sm.red[kk][rr][bb];
        gstore(&h1g[(size_t)(2 * w + rr) * 32 + bb], fmaxf(s, 0.0f));
      }
    }
    gridbar(flags, ++ep, dead);

    // ========== P6: FC2 fine row-split + partial argmax (w<32) ==========
    if (isHead) {
      const int k0 = ks * 28;
      float acc[8];
#pragma unroll
      for (int rr = 0; rr < 8; rr++) acc[rr] = 0.0f;
      const float* hh = h1g + b;
#pragma unroll
      for (int k = k0; k < k0 + 28; k += 4) {
        float h0 = gload(&hh[(k + 0) * 32]), h1v = gload(&hh[(k + 1) * 32]);
        float h2 = gload(&hh[(k + 2) * 32]), h3  = gload(&hh[(k + 3) * 32]);
#pragma unroll
        for (int rr = 0; rr < 8; rr++) {
          const float4 wv = *(const float4*)&sm.wf2l[rr][k];
          acc[rr] = fmaf(wv.x, h0, fmaf(wv.y, h1v, fmaf(wv.z, h2, fmaf(wv.w, h3, acc[rr]))));
        }
      }
#pragma unroll
      for (int rr = 0; rr < 8; rr++) acc[rr] += __shfl_xor(acc[rr], 32);
      __syncthreads();
      if ((tid & 32) == 0) {
        int slot = ks >> 1;
#pragma unroll
        for (int rr = 0; rr < 8; rr++) sm.red[slot][rr][b] = acc[rr];
      }
      __syncthreads();
      if (tid < 256) {
        int rr = tid >> 5, bb = tid & 31;
        float s = bf2[w * 8 + rr];
#pragma unroll
        for (int kk = 0; kk < 8; kk++) s += sm.red[kk][rr][bb];
        sm.logit8[rr][bb] = s;
      }
      __syncthreads();
      if (tid < 32) {
        float bv = sm.logit8[0][tid]; int bi = 0;
#pragma unroll
        for (int rr = 1; rr < 8; rr++) {
          float x = sm.logit8[rr][tid];
          if (x > bv) { bv = x; bi = rr; }
        }
        gstore(&candf[(w * 32 + tid) * 2], bv);
        gstore(&candf[(w * 32 + tid) * 2 + 1], (float)(w * 8 + bi));
      }
    }
    gridbar(flags, ++ep, dead);
  }

  // ===== epilogue: nf(1023) + final hidden =====
  if (isHead) {
    const int b2 = w;
    float v = -3.4e38f; float vi = 2.14e9f;
    if (tid < 32) {
      v  = gload(&candf[(tid * 32 + b2) * 2]);
      vi = gload(&candf[(tid * 32 + b2) * 2 + 1]);
    }
    if (tid < 64) {
#pragma unroll
      for (int off = 16; off >= 1; off >>= 1) {
        float ov = __shfl_xor(v, off); float oi = __shfl_xor(vi, off);
        if (ov > v || (ov == v && oi < vi)) { v = ov; vi = oi; }
      }
      if (tid == 0) out[32768 + (size_t)b2 * TSTEPS + (TSTEPS - 1)] = vi;
    }
    if (tid < HALFN)
      out[65536 + (size_t)(HALFN + tid) * 32 + b2] = sm.fhid[tid];
  }
  if (tid < 64) {
    int q = tid >> 5, bb = tid & 31;
    out[65536 + (size_t)(2 * w + q) * 32 + bb] = sm.chid[q][bb];
  }
}

extern "C" void kernel_launch(void* const* d_in, const int* in_sizes, int n_in,
                              void* d_out, int out_size, void* d_ws, size_t ws_size,
                              hipStream_t stream) {
  const float* cond = (const float*)d_in[0];
  const float* wci  = (const float*)d_in[1];
  const float* wfi  = (const float*)d_in[2];
  const float* whh  = (const float*)d_in[3];
  const float* bih  = (const float*)d_in[4];
  const float* bhh  = (const float*)d_in[5];
  const float* wc1  = (const float*)d_in[6];
  const float* bc1  = (const float*)d_in[7];
  const float* wc2  = (const float*)d_in[8];
  const float* bc2  = (const float*)d_in[9];
  const float* wf1  = (const float*)d_in[10];
  const float* bf1  = (const float*)d_in[11];
  const float* wf2  = (const float*)d_in[12];
  const float* bf2  = (const float*)d_in[13];
  float* out = (float*)d_out;
  float* ws  = (float*)d_ws;

  hipLaunchKernelGGL(wavernn_init, dim3(64), dim3(256), 0, stream, ws);
  hipLaunchKernelGGL(wavernn_persist, dim3(NWG), dim3(NTHR), 0, stream,
                     cond, wci, wfi, whh, bih, bhh,
                     wc1, bc1, wc2, bc2, wf1, bf1, wf2, bf2, out, ws);
}

// Round 7
// 34736.581 us; speedup vs baseline: 2.7441x; 1.2129x over previous
//
#include <hip/hip_runtime.h>
#include <math.h>

// WaveRNN autoregressive sampler, persistent kernel, fp32. Round 7:
// 4 full grid barriers + 2 single-address counter polls per step (was 6 bars).
// - GEMM gate outputs stay in LDS (hp never round-trips global).
// - FC2 argmax via packed u64 atomicMax (ord(float)<<32 | ~idx) + done-counter;
//   consumers poll ONE address instead of a 224-flag barrier.
// - FC2f (heads) overlaps with next step's GEMM (non-heads start immediately
//   after bar4; nf consumed after a poll inside phase A).
// - fGRU distributed across all 224 WGs (j=2w,2w+1), samples kept in LDS.
// Round-6 evidence: VALUBusy 14%, HBM 1.8% -> serial phase/barrier structure
// dominates (6.8us per phase+barrier). This attacks the structure.

#define HALFN  448
#define SIZEN  896
#define RTOT   2688
#define NB     32
#define TSTEPS 1024
#define NWG    224
#define NTHR   512
#define CONDSTR (RTOT * TSTEPS)

// ws float offsets
#define OFF_HID0  0         // [896*32] hid[j*32+b], buffer A
#define OFF_HID1  28672     // buffer B
#define OFF_H1GC  57344     // [448*32] FC1c output
#define OFF_H1GF  71680     // [448*32] FC1f output
#define OFF_NCP   86016     // 32 x u64 packed coarse argmax
#define OFF_NFP   86080     // 32 x u64 packed fine argmax
#define OFF_CTR   86144     // [0]=ncCtr [1]=nfCtr (uint)
#define OFF_FLAGS 86400     // 256 barrier flags (uint)

typedef unsigned long long u64t;

__device__ __forceinline__ int orig_row(int r) {   // reordered -> original
  int c = r / HALFN, o = r - c * HALFN;
  int oc = (c < 3) ? (2 * c) : (2 * (c - 3) + 1);
  return oc * HALFN + o;
}
__device__ __forceinline__ float sigm(float x) { return 1.0f / (1.0f + expf(-x)); }

__device__ __forceinline__ float gload(const float* p) {
  return __hip_atomic_load(const_cast<float*>(p), __ATOMIC_RELAXED, __HIP_MEMORY_SCOPE_AGENT);
}
__device__ __forceinline__ void gstore(float* p, float v) {
  __hip_atomic_store(p, v, __ATOMIC_RELAXED, __HIP_MEMORY_SCOPE_AGENT);
}
__device__ __forceinline__ u64t gload64(const u64t* p) {
  return __hip_atomic_load(const_cast<u64t*>(p), __ATOMIC_RELAXED, __HIP_MEMORY_SCOPE_AGENT);
}
__device__ __forceinline__ void gstore64(u64t* p, u64t v) {
  __hip_atomic_store(p, v, __ATOMIC_RELAXED, __HIP_MEMORY_SCOPE_AGENT);
}
__device__ __forceinline__ void gmax64(u64t* p, u64t v) {
  __hip_atomic_fetch_max(p, v, __ATOMIC_RELAXED, __HIP_MEMORY_SCOPE_AGENT);
}
__device__ __forceinline__ unsigned ctrload(const unsigned* p) {
  return __hip_atomic_load(const_cast<unsigned*>(p), __ATOMIC_RELAXED, __HIP_MEMORY_SCOPE_AGENT);
}
// order-preserving float->uint (finite inputs)
__device__ __forceinline__ unsigned f2ord(float f) {
  unsigned u = __float_as_uint(f);
  return (u & 0x80000000u) ? ~u : (u | 0x80000000u);
}

struct __align__(16) SM {
  float whh[12][SIZEN];     // 43008 rows {c*448+2w, +1}, c=0..5
  float wc1l[2][HALFN];     // 3584
  float wf1l[2][HALFN];     // 3584
  float wc2l[8][HALFN];     // 14336 (heads)
  float wf2l[8][HALFN];     // 14336 (heads)
  float red[8][12][32];     // 12288
  float hps[6][32];         // coarse hp gates (r0,r1,u0,u1,e0,e1)
  float hpfl[6][32];        // fine hp gates
  float chid[2][32];        // persistent c_hid rows 2w,2w+1
  float fhid[2][32];        // persistent f_hid rows 2w,2w+1
  float scvo[32];           // scale(nc(t-1))
  float sfvo[32];           // scale(nf(t-1))
  float sncn[32];           // scale(nc(t))
  float logit8[8][32];
  float bhh_l[12];
  int   pflag;
};

__device__ __forceinline__ void gridbar(unsigned* flags, unsigned ep, int& dead) {
  asm volatile("s_waitcnt vmcnt(0)" ::: "memory");
  __syncthreads();
  if (threadIdx.x == 0)
    __hip_atomic_store(&flags[blockIdx.x], ep, __ATOMIC_RELAXED, __HIP_MEMORY_SCOPE_AGENT);
  if (!dead) {
    int iters = 0;
    for (;;) {
      int ok = 1;
      if (threadIdx.x < NWG) {
        unsigned v = __hip_atomic_load(&flags[threadIdx.x], __ATOMIC_RELAXED, __HIP_MEMORY_SCOPE_AGENT);
        ok = (v >= ep) ? 1 : 0;
      }
      if (__syncthreads_and(ok)) break;
      if (++iters > (1 << 20)) { dead = 1; break; }
      __builtin_amdgcn_s_sleep(1);
    }
  } else {
    __syncthreads();
  }
}

// single-address counter poll (whole WG participates)
__device__ __forceinline__ void pollctr(unsigned* ctr, unsigned target, int* pf, int& dead) {
  if (!dead) {
    int it = 0;
    for (;;) {
      if (threadIdx.x == 0) *pf = (ctrload(ctr) >= target) ? 1 : 0;
      __syncthreads();
      int f = *pf;
      __syncthreads();
      if (f) break;
      if (++it > (1 << 20)) { dead = 1; break; }
      __builtin_amdgcn_s_sleep(1);
    }
  } else {
    __syncthreads(); __syncthreads();
  }
}

extern "C" __global__ void wavernn_init(float* ws) {
  int i = blockIdx.x * blockDim.x + threadIdx.x;
  int st = gridDim.x * blockDim.x;
  for (int k = i; k < 2 * SIZEN * NB; k += st) ws[k] = 0.0f;     // both hid buffers
  if (i < 64) ((u64t*)(ws + OFF_NCP))[i] = 0ull;                 // ncp+nfp
  if (i < 2) ((unsigned*)(ws + OFF_CTR))[i] = 0u;
  if (i < 256) ((unsigned*)(ws + OFF_FLAGS))[i] = 0u;
}

extern "C" __global__ void __launch_bounds__(NTHR)
wavernn_persist(const float* __restrict__ cond,
                const float* __restrict__ wci, const float* __restrict__ wfi,
                const float* __restrict__ whh, const float* __restrict__ bih,
                const float* __restrict__ bhh,
                const float* __restrict__ wc1, const float* __restrict__ bc1,
                const float* __restrict__ wc2, const float* __restrict__ bc2,
                const float* __restrict__ wf1, const float* __restrict__ bf1,
                const float* __restrict__ wf2, const float* __restrict__ bf2,
                float* __restrict__ out, float* ws) {
  __shared__ SM sm;

  float* hid0 = ws + OFF_HID0;
  float* hid1 = ws + OFF_HID1;
  float* h1gc = ws + OFF_H1GC;
  float* h1gf = ws + OFF_H1GF;
  u64t*  ncp  = (u64t*)(ws + OFF_NCP);
  u64t*  nfp  = (u64t*)(ws + OFF_NFP);
  unsigned* ctr = (unsigned*)(ws + OFF_CTR);   // [0]=nc [1]=nf
  unsigned* flags = (unsigned*)(ws + OFF_FLAGS);

  const int w = blockIdx.x, tid = threadIdx.x;
  const int b = tid & 31, ks = tid >> 5;     // 16 k-slices x 32 batch
  const bool isHead = (w < NB);
  unsigned ep = 0;
  int dead = 0;

  // ---------- one-time LDS staging ----------
#pragma unroll
  for (int rr = 0; rr < 12; rr++) {
    int R = (rr >> 1) * HALFN + 2 * w + (rr & 1);
    const float* src = whh + (size_t)orig_row(R) * SIZEN;
    for (int k = tid * 4; k < SIZEN; k += NTHR * 4)
      *(float4*)&sm.whh[rr][k] = *(const float4*)&src[k];
  }
  if (tid < 12) sm.bhh_l[tid] = bhh[orig_row((tid >> 1) * HALFN + 2 * w + (tid & 1))];
  for (int k = tid * 4; k < HALFN; k += NTHR * 4) {
    *(float4*)&sm.wc1l[0][k] = *(const float4*)&wc1[(size_t)(2 * w) * HALFN + k];
    *(float4*)&sm.wc1l[1][k] = *(const float4*)&wc1[(size_t)(2 * w + 1) * HALFN + k];
    *(float4*)&sm.wf1l[0][k] = *(const float4*)&wf1[(size_t)(2 * w) * HALFN + k];
    *(float4*)&sm.wf1l[1][k] = *(const float4*)&wf1[(size_t)(2 * w + 1) * HALFN + k];
  }
  if (isHead) {
#pragma unroll
    for (int rr = 0; rr < 8; rr++) {
      for (int k = tid * 4; k < HALFN; k += NTHR * 4) {
        *(float4*)&sm.wc2l[rr][k] = *(const float4*)&wc2[(size_t)(w * 8 + rr) * HALFN + k];
        *(float4*)&sm.wf2l[rr][k] = *(const float4*)&wf2[(size_t)(w * 8 + rr) * HALFN + k];
      }
    }
  }
  if (tid < 64) { sm.chid[tid >> 5][tid & 31] = 0.0f; sm.fhid[tid >> 5][tid & 31] = 0.0f; }
  if (tid < 32) { sm.scvo[tid] = 128.0f * (2.0f / 255.0f) - 1.0f; sm.sfvo[tid] = -1.0f; }
  __syncthreads();

  for (int t = 0; t < TSTEPS; ++t) {
    const float* hprev = (t & 1) ? hid0 : hid1;
    float*       hcur  = (t & 1) ? hid1 : hid0;

    // ========== A: GEMM (hp stays in LDS) + nf-poll + coarse GRU ==========
    {
      float acc[12];
#pragma unroll
      for (int rr = 0; rr < 12; rr++) acc[rr] = 0.0f;
      const int k0 = ks * 56;
      const float* hcol = hprev + b;
#pragma unroll 2
      for (int k = k0; k < k0 + 56; k += 4) {
        float h0 = gload(&hcol[(k + 0) * 32]), h1v = gload(&hcol[(k + 1) * 32]);
        float h2 = gload(&hcol[(k + 2) * 32]), h3  = gload(&hcol[(k + 3) * 32]);
#pragma unroll
        for (int rr = 0; rr < 12; rr++) {
          const float4 wv = *(const float4*)&sm.whh[rr][k];
          acc[rr] = fmaf(wv.x, h0, fmaf(wv.y, h1v, fmaf(wv.z, h2, fmaf(wv.w, h3, acc[rr]))));
        }
      }
#pragma unroll
      for (int rr = 0; rr < 12; rr++) acc[rr] += __shfl_xor(acc[rr], 32);
      __syncthreads();   // red reuse fence (covers heads' F-phase reads)
      if ((tid & 32) == 0) {
        int slot = ks >> 1;
#pragma unroll
        for (int rr = 0; rr < 12; rr++) sm.red[slot][rr][b] = acc[rr];
      }
      __syncthreads();
      if (tid < 384) {
        int rr = tid >> 5, bb = tid & 31;
        float s = sm.bhh_l[rr];
#pragma unroll
        for (int kk = 0; kk < 8; kk++) s += sm.red[kk][rr][bb];
        if (rr < 6) sm.hps[rr][bb] = s;
        else        sm.hpfl[rr - 6][bb] = s;
      }
      // nf(t-1): single-address poll (heads computed it overlapped with our GEMM)
      if (t > 0) {
        pollctr(&ctr[1], 32u * (unsigned)t, &sm.pflag, dead);
        if (tid < 32) {
          u64t p = gload64(&nfp[tid]);
          unsigned nf = 0xFFFFFFFFu - (unsigned)(p & 0xFFFFFFFFull);
          sm.sfvo[tid] = (float)nf * (2.0f / 255.0f) - 1.0f;
          if (isHead && tid == w) out[32768 + (size_t)w * TSTEPS + (t - 1)] = (float)nf;
        }
      }
      __syncthreads();
      // coarse GRU for j = 2w, 2w+1 (hp rows are LDS-local)
      if (tid < 64) {
        int q = tid >> 5, bb = tid & 31;
        int j = 2 * w + q;
        float sc = sm.scvo[bb], sf = sm.sfvo[bb];
        float ipr = wci[j * 2] * sc + wci[j * 2 + 1] * sf
                  + cond[(size_t)bb * CONDSTR + (size_t)j * TSTEPS + t] + bih[j];
        float ipu = wci[(HALFN + j) * 2] * sc + wci[(HALFN + j) * 2 + 1] * sf
                  + cond[(size_t)bb * CONDSTR + (size_t)(SIZEN + j) * TSTEPS + t] + bih[SIZEN + j];
        float ipe = wci[(SIZEN + j) * 2] * sc + wci[(SIZEN + j) * 2 + 1] * sf
                  + cond[(size_t)bb * CONDSTR + (size_t)(1792 + j) * TSTEPS + t] + bih[1792 + j];
        float r = sigm(sm.hps[0 + q][bb] + ipr);
        float u = sigm(sm.hps[2 + q][bb] + ipu);
        float e = tanhf(fmaf(r, sm.hps[4 + q][bb], ipe));
        float hnew = u * sm.chid[q][bb] + (1.0f - u) * e;
        sm.chid[q][bb] = hnew;
        gstore(&hcur[(size_t)j * 32 + bb], hnew);
      }
    }
    gridbar(flags, ++ep, dead);                       // bar1: h_c ready

    // ========== B: FC1 coarse (rows 2w,2w+1) ==========
    {
      const int k0 = ks * 28;
      float a0 = 0.0f, a1 = 0.0f;
      const float* hcc = hcur + b;
#pragma unroll
      for (int k = k0; k < k0 + 28; k += 4) {
        float h0 = gload(&hcc[(k + 0) * 32]), h1v = gload(&hcc[(k + 1) * 32]);
        float h2 = gload(&hcc[(k + 2) * 32]), h3  = gload(&hcc[(k + 3) * 32]);
        float4 v0 = *(const float4*)&sm.wc1l[0][k];
        a0 = fmaf(v0.x, h0, fmaf(v0.y, h1v, fmaf(v0.z, h2, fmaf(v0.w, h3, a0))));
        float4 v1 = *(const float4*)&sm.wc1l[1][k];
        a1 = fmaf(v1.x, h0, fmaf(v1.y, h1v, fmaf(v1.z, h2, fmaf(v1.w, h3, a1))));
      }
      a0 += __shfl_xor(a0, 32); a1 += __shfl_xor(a1, 32);
      __syncthreads();
      if ((tid & 32) == 0) { sm.red[ks >> 1][0][b] = a0; sm.red[ks >> 1][1][b] = a1; }
      if (isHead && tid == 256) gstore64(&ncp[w], 0ull);   // reset this step's pack
      __syncthreads();
      if (tid < 64) {
        int rr = tid >> 5, bb = tid & 31;
        float s = bc1[2 * w + rr];
#pragma unroll
        for (int kk = 0; kk < 8; kk++) s += sm.red[kk][rr][bb];
        gstore(&h1gc[(size_t)(2 * w + rr) * 32 + bb], fmaxf(s, 0.0f));
      }
    }
    gridbar(flags, ++ep, dead);                       // bar2: h1c ready

    // ========== C: FC2 coarse (heads) -> packed atomicMax + counter ==========
    if (isHead) {
      const int k0 = ks * 28;
      float acc[8];
#pragma unroll
      for (int rr = 0; rr < 8; rr++) acc[rr] = 0.0f;
      const float* hh = h1gc + b;
#pragma unroll
      for (int k = k0; k < k0 + 28; k += 4) {
        float h0 = gload(&hh[(k + 0) * 32]), h1v = gload(&hh[(k + 1) * 32]);
        float h2 = gload(&hh[(k + 2) * 32]), h3  = gload(&hh[(k + 3) * 32]);
#pragma unroll
        for (int rr = 0; rr < 8; rr++) {
          const float4 wv = *(const float4*)&sm.wc2l[rr][k];
          acc[rr] = fmaf(wv.x, h0, fmaf(wv.y, h1v, fmaf(wv.z, h2, fmaf(wv.w, h3, acc[rr]))));
        }
      }
#pragma unroll
      for (int rr = 0; rr < 8; rr++) acc[rr] += __shfl_xor(acc[rr], 32);
      __syncthreads();
      if ((tid & 32) == 0) {
        int slot = ks >> 1;
#pragma unroll
        for (int rr = 0; rr < 8; rr++) sm.red[slot][rr][b] = acc[rr];
      }
      __syncthreads();
      if (tid < 256) {
        int rr = tid >> 5, bb = tid & 31;
        float s = bc2[w * 8 + rr];
#pragma unroll
        for (int kk = 0; kk < 8; kk++) s += sm.red[kk][rr][bb];
        sm.logit8[rr][bb] = s;
      }
      __syncthreads();
      if (tid < 32) {
        float bv = sm.logit8[0][tid]; int bi = 0;
#pragma unroll
        for (int rr = 1; rr < 8; rr++) {
          float x = sm.logit8[rr][tid];
          if (x > bv) { bv = x; bi = rr; }
        }
        u64t pack = ((u64t)f2ord(bv) << 32) | (u64t)(0xFFFFFFFFu - (unsigned)(w * 8 + bi));
        gmax64(&ncp[tid], pack);
      }
      asm volatile("s_waitcnt vmcnt(0)" ::: "memory");
      __syncthreads();
      if (tid == 0) __hip_atomic_fetch_add(&ctr[0], 1u, __ATOMIC_RELAXED, __HIP_MEMORY_SCOPE_AGENT);
    }
    pollctr(&ctr[0], 32u * (unsigned)(t + 1), &sm.pflag, dead);   // nc ready

    // ========== D: fine GRU (all WGs, j=2w,2w+1) ==========
    {
      if (tid < 32) {
        u64t p = gload64(&ncp[tid]);
        unsigned nc = 0xFFFFFFFFu - (unsigned)(p & 0xFFFFFFFFull);
        sm.sncn[tid] = (float)nc * (2.0f / 255.0f) - 1.0f;
        if (isHead && tid == w) out[(size_t)w * TSTEPS + t] = (float)nc;
      }
      __syncthreads();
      if (tid < 64) {
        int q = tid >> 5, bb = tid & 31;
        int j = 2 * w + q;
        float sc = sm.scvo[bb], sf = sm.sfvo[bb], snc = sm.sncn[bb];
        float ipr = wfi[j * 3] * sc + wfi[j * 3 + 1] * sf + wfi[j * 3 + 2] * snc
                  + cond[(size_t)bb * CONDSTR + (size_t)(HALFN + j) * TSTEPS + t] + bih[HALFN + j];
        float ipu = wfi[(HALFN + j) * 3] * sc + wfi[(HALFN + j) * 3 + 1] * sf + wfi[(HALFN + j) * 3 + 2] * snc
                  + cond[(size_t)bb * CONDSTR + (size_t)(1344 + j) * TSTEPS + t] + bih[1344 + j];
        float ipe = wfi[(SIZEN + j) * 3] * sc + wfi[(SIZEN + j) * 3 + 1] * sf + wfi[(SIZEN + j) * 3 + 2] * snc
                  + cond[(size_t)bb * CONDSTR + (size_t)(2240 + j) * TSTEPS + t] + bih[2240 + j];
        float r = sigm(sm.hpfl[0 + q][bb] + ipr);
        float u = sigm(sm.hpfl[2 + q][bb] + ipu);
        float e = tanhf(fmaf(r, sm.hpfl[4 + q][bb], ipe));
        float hnew = u * sm.fhid[q][bb] + (1.0f - u) * e;
        sm.fhid[q][bb] = hnew;
        gstore(&hcur[(size_t)(HALFN + j) * 32 + bb], hnew);
      }
      __syncthreads();
      if (tid < 32) sm.scvo[tid] = sm.sncn[tid];   // commit nc(t) as old coarse sample
    }
    gridbar(flags, ++ep, dead);                       // bar3: h_f ready

    // ========== E: FC1 fine (rows 2w,2w+1) ==========
    {
      const int k0 = ks * 28;
      float a0 = 0.0f, a1 = 0.0f;
      const float* hff = hcur + HALFN * 32 + b;
#pragma unroll
      for (int k = k0; k < k0 + 28; k += 4) {
        float h0 = gload(&hff[(k + 0) * 32]), h1v = gload(&hff[(k + 1) * 32]);
        float h2 = gload(&hff[(k + 2) * 32]), h3  = gload(&hff[(k + 3) * 32]);
        float4 v0 = *(const float4*)&sm.wf1l[0][k];
        a0 = fmaf(v0.x, h0, fmaf(v0.y, h1v, fmaf(v0.z, h2, fmaf(v0.w, h3, a0))));
        float4 v1 = *(const float4*)&sm.wf1l[1][k];
        a1 = fmaf(v1.x, h0, fmaf(v1.y, h1v, fmaf(v1.z, h2, fmaf(v1.w, h3, a1))));
      }
      a0 += __shfl_xor(a0, 32); a1 += __shfl_xor(a1, 32);
      __syncthreads();
      if ((tid & 32) == 0) { sm.red[ks >> 1][0][b] = a0; sm.red[ks >> 1][1][b] = a1; }
      if (isHead && tid == 256) gstore64(&nfp[w], 0ull);   // reset this step's pack
      __syncthreads();
      if (tid < 64) {
        int rr = tid >> 5, bb = tid & 31;
        float s = bf1[2 * w + rr];
#pragma unroll
        for (int kk = 0; kk < 8; kk++) s += sm.red[kk][rr][bb];
        gstore(&h1gf[(size_t)(2 * w + rr) * 32 + bb], fmaxf(s, 0.0f));
      }
    }
    gridbar(flags, ++ep, dead);                       // bar4: h1f ready

    // ========== F: FC2 fine (heads) — overlaps next step's GEMM ==========
    if (isHead) {
      const int k0 = ks * 28;
      float acc[8];
#pragma unroll
      for (int rr = 0; rr < 8; rr++) acc[rr] = 0.0f;
      const float* hh = h1gf + b;
#pragma unroll
      for (int k = k0; k < k0 + 28; k += 4) {
        float h0 = gload(&hh[(k + 0) * 32]), h1v = gload(&hh[(k + 1) * 32]);
        float h2 = gload(&hh[(k + 2) * 32]), h3  = gload(&hh[(k + 3) * 32]);
#pragma unroll
        for (int rr = 0; rr < 8; rr++) {
          const float4 wv = *(const float4*)&sm.wf2l[rr][k];
          acc[rr] = fmaf(wv.x, h0, fmaf(wv.y, h1v, fmaf(wv.z, h2, fmaf(wv.w, h3, acc[rr]))));
        }
      }
#pragma unroll
      for (int rr = 0; rr < 8; rr++) acc[rr] += __shfl_xor(acc[rr], 32);
      __syncthreads();
      if ((tid & 32) == 0) {
        int slot = ks >> 1;
#pragma unroll
        for (int rr = 0; rr < 8; rr++) sm.red[slot][rr][b] = acc[rr];
      }
      __syncthreads();
      if (tid < 256) {
        int rr = tid >> 5, bb = tid & 31;
        float s = bf2[w * 8 + rr];
#pragma unroll
        for (int kk = 0; kk < 8; kk++) s += sm.red[kk][rr][bb];
        sm.logit8[rr][bb] = s;
      }
      __syncthreads();
      if (tid < 32) {
        float bv = sm.logit8[0][tid]; int bi = 0;
#pragma unroll
        for (int rr = 1; rr < 8; rr++) {
          float x = sm.logit8[rr][tid];
          if (x > bv) { bv = x; bi = rr; }
        }
        u64t pack = ((u64t)f2ord(bv) << 32) | (u64t)(0xFFFFFFFFu - (unsigned)(w * 8 + bi));
        gmax64(&nfp[tid], pack);
      }
      asm volatile("s_waitcnt vmcnt(0)" ::: "memory");
      __syncthreads();
      if (tid == 0) __hip_atomic_fetch_add(&ctr[1], 1u, __ATOMIC_RELAXED, __HIP_MEMORY_SCOPE_AGENT);
    }
    // no barrier: non-heads already started next GEMM; nf consumed via poll in A
  }

  // ===== epilogue: nf(1023) + final hidden =====
  pollctr(&ctr[1], 32u * (unsigned)TSTEPS, &sm.pflag, dead);
  if (tid < 32 && isHead && tid == w) {
    u64t p = gload64(&nfp[tid]);
    unsigned nf = 0xFFFFFFFFu - (unsigned)(p & 0xFFFFFFFFull);
    out[32768 + (size_t)w * TSTEPS + (TSTEPS - 1)] = (float)nf;
  }
  if (tid < 64) {
    int q = tid >> 5, bb = tid & 31;
    out[65536 + (size_t)(2 * w + q) * 32 + bb]         = sm.chid[q][bb];
    out[65536 + (size_t)(HALFN + 2 * w + q) * 32 + bb] = sm.fhid[q][bb];
  }
}

extern "C" void kernel_launch(void* const* d_in, const int* in_sizes, int n_in,
                              void* d_out, int out_size, void* d_ws, size_t ws_size,
                              hipStream_t stream) {
  const float* cond = (const float*)d_in[0];
  const float* wci  = (const float*)d_in[1];
  const float* wfi  = (const float*)d_in[2];
  const float* whh  = (const float*)d_in[3];
  const float* bih  = (const float*)d_in[4];
  const float* bhh  = (const float*)d_in[5];
  const float* wc1  = (const float*)d_in[6];
  const float* bc1  = (const float*)d_in[7];
  const float* wc2  = (const float*)d_in[8];
  const float* bc2  = (const float*)d_in[9];
  const float* wf1  = (const float*)d_in[10];
  const float* bf1  = (const float*)d_in[11];
  const float* wf2  = (const float*)d_in[12];
  const float* bf2  = (const float*)d_in[13];
  float* out = (float*)d_out;
  float* ws  = (float*)d_ws;

  hipLaunchKernelGGL(wavernn_init, dim3(64), dim3(256), 0, stream, ws);
  hipLaunchKernelGGL(wavernn_persist, dim3(NWG), dim3(NTHR), 0, stream,
                     cond, wci, wfi, whh, bih, bhh,
                     wc1, bc1, wc2, bc2, wf1, bf1, wf2, bf2, out, ws);
}

// Round 8
// 31059.198 us; speedup vs baseline: 3.0690x; 1.1184x over previous
//
#include <hip/hip_runtime.h>
#include <math.h>

// WaveRNN autoregressive sampler, persistent kernel, fp32. Round 8:
// round-7 structure (4 barriers + 2 counter polls, FC2f overlapped with next
// GEMM) + cond STAGED IN LDS in 16-step windows + per-WG wci/wfi/bih slices
// in LDS. Round-7 counters showed FETCH = 6.4 MB/step == the entire cond
// live window re-fetched from HBM every step (L2 stream-thrash: 12.8 MB
// streams through 4 MB per-XCD L2 within a line's 16-step reuse window),
// latency-exposed inside the critical-path GRU phases. After this, steady
// state global traffic = sc1 state exchange only; cond streams HBM once.

#define HALFN  448
#define SIZEN  896
#define RTOT   2688
#define NB     32
#define TSTEPS 1024
#define NWG    224
#define NTHR   512
#define CONDSTR (RTOT * TSTEPS)

// ws float offsets
#define OFF_HID0  0         // [896*32] hid[j*32+b], buffer A
#define OFF_HID1  28672     // buffer B
#define OFF_H1GC  57344     // [448*32] FC1c output
#define OFF_H1GF  71680     // [448*32] FC1f output
#define OFF_NCP   86016     // 32 x u64 packed coarse argmax
#define OFF_NFP   86080     // 32 x u64 packed fine argmax
#define OFF_CTR   86144     // [0]=ncCtr [1]=nfCtr (uint)
#define OFF_FLAGS 86400     // 256 barrier flags (uint)

typedef unsigned long long u64t;

__device__ __forceinline__ int orig_row(int r) {   // reordered -> original
  int c = r / HALFN, o = r - c * HALFN;
  int oc = (c < 3) ? (2 * c) : (2 * (c - 3) + 1);
  return oc * HALFN + o;
}
__device__ __forceinline__ float sigm(float x) { return 1.0f / (1.0f + expf(-x)); }

__device__ __forceinline__ float gload(const float* p) {
  return __hip_atomic_load(const_cast<float*>(p), __ATOMIC_RELAXED, __HIP_MEMORY_SCOPE_AGENT);
}
__device__ __forceinline__ void gstore(float* p, float v) {
  __hip_atomic_store(p, v, __ATOMIC_RELAXED, __HIP_MEMORY_SCOPE_AGENT);
}
__device__ __forceinline__ u64t gload64(const u64t* p) {
  return __hip_atomic_load(const_cast<u64t*>(p), __ATOMIC_RELAXED, __HIP_MEMORY_SCOPE_AGENT);
}
__device__ __forceinline__ void gstore64(u64t* p, u64t v) {
  __hip_atomic_store(p, v, __ATOMIC_RELAXED, __HIP_MEMORY_SCOPE_AGENT);
}
__device__ __forceinline__ void gmax64(u64t* p, u64t v) {
  __hip_atomic_fetch_max(p, v, __ATOMIC_RELAXED, __HIP_MEMORY_SCOPE_AGENT);
}
__device__ __forceinline__ unsigned ctrload(const unsigned* p) {
  return __hip_atomic_load(const_cast<unsigned*>(p), __ATOMIC_RELAXED, __HIP_MEMORY_SCOPE_AGENT);
}
// order-preserving float->uint (finite inputs)
__device__ __forceinline__ unsigned f2ord(float f) {
  unsigned u = __float_as_uint(f);
  return (u & 0x80000000u) ? ~u : (u | 0x80000000u);
}

struct __align__(16) SM {
  float whh[12][SIZEN];     // 43008 rows {c*448+2w, +1}, c=0..5
  float wc1l[2][HALFN];     // 3584
  float wf1l[2][HALFN];     // 3584
  float wc2l[8][HALFN];     // 14336 (heads)
  float wf2l[8][HALFN];     // 14336 (heads)
  float red[8][12][32];     // 12288
  float condw[12][16][33];  // 25344: 16-step cond window, [rk][t&15][b]
                            // rk = (fine?6:0) + g*2 + q ; R = (fine?448:0)+g*896+2w+q
  float hps[6][32];         // coarse hp gates (r0,r1,u0,u1,e0,e1)
  float hpfl[6][32];        // fine hp gates
  float chid[2][32];        // persistent c_hid rows 2w,2w+1
  float fhid[2][32];        // persistent f_hid rows 2w,2w+1
  float scvo[32];           // scale(nc(t-1))
  float sfvo[32];           // scale(nf(t-1))
  float sncn[32];           // scale(nc(t))
  float logit8[8][32];
  float wcil[2][3][2];      // wci rows {g*448+2w+q}
  float wfil[2][3][3];      // wfi rows {g*448+2w+q}
  float bihl[12];           // bih[R(rk)]
  float bhh_l[12];
  int   pflag;
};

__device__ __forceinline__ void gridbar(unsigned* flags, unsigned ep, int& dead) {
  asm volatile("s_waitcnt vmcnt(0)" ::: "memory");
  __syncthreads();
  if (threadIdx.x == 0)
    __hip_atomic_store(&flags[blockIdx.x], ep, __ATOMIC_RELAXED, __HIP_MEMORY_SCOPE_AGENT);
  if (!dead) {
    int iters = 0;
    for (;;) {
      int ok = 1;
      if (threadIdx.x < NWG) {
        unsigned v = __hip_atomic_load(&flags[threadIdx.x], __ATOMIC_RELAXED, __HIP_MEMORY_SCOPE_AGENT);
        ok = (v >= ep) ? 1 : 0;
      }
      if (__syncthreads_and(ok)) break;
      if (++iters > (1 << 20)) { dead = 1; break; }
      __builtin_amdgcn_s_sleep(1);
    }
  } else {
    __syncthreads();
  }
}

// single-address counter poll (whole WG participates)
__device__ __forceinline__ void pollctr(unsigned* ctr, unsigned target, int* pf, int& dead) {
  if (!dead) {
    int it = 0;
    for (;;) {
      if (threadIdx.x == 0) *pf = (ctrload(ctr) >= target) ? 1 : 0;
      __syncthreads();
      int f = *pf;
      __syncthreads();
      if (f) break;
      if (++it > (1 << 20)) { dead = 1; break; }
      __builtin_amdgcn_s_sleep(1);
    }
  } else {
    __syncthreads(); __syncthreads();
  }
}

extern "C" __global__ void wavernn_init(float* ws) {
  int i = blockIdx.x * blockDim.x + threadIdx.x;
  int st = gridDim.x * blockDim.x;
  for (int k = i; k < 2 * SIZEN * NB; k += st) ws[k] = 0.0f;     // both hid buffers
  if (i < 64) ((u64t*)(ws + OFF_NCP))[i] = 0ull;                 // ncp+nfp
  if (i < 2) ((unsigned*)(ws + OFF_CTR))[i] = 0u;
  if (i < 256) ((unsigned*)(ws + OFF_FLAGS))[i] = 0u;
}

extern "C" __global__ void __launch_bounds__(NTHR)
wavernn_persist(const float* __restrict__ cond,
                const float* __restrict__ wci, const float* __restrict__ wfi,
                const float* __restrict__ whh, const float* __restrict__ bih,
                const float* __restrict__ bhh,
                const float* __restrict__ wc1, const float* __restrict__ bc1,
                const float* __restrict__ wc2, const float* __restrict__ bc2,
                const float* __restrict__ wf1, const float* __restrict__ bf1,
                const float* __restrict__ wf2, const float* __restrict__ bf2,
                float* __restrict__ out, float* ws) {
  __shared__ SM sm;

  float* hid0 = ws + OFF_HID0;
  float* hid1 = ws + OFF_HID1;
  float* h1gc = ws + OFF_H1GC;
  float* h1gf = ws + OFF_H1GF;
  u64t*  ncp  = (u64t*)(ws + OFF_NCP);
  u64t*  nfp  = (u64t*)(ws + OFF_NFP);
  unsigned* ctr = (unsigned*)(ws + OFF_CTR);   // [0]=nc [1]=nf
  unsigned* flags = (unsigned*)(ws + OFF_FLAGS);

  const int w = blockIdx.x, tid = threadIdx.x;
  const int b = tid & 31, ks = tid >> 5;     // 16 k-slices x 32 batch
  const bool isHead = (w < NB);
  unsigned ep = 0;
  int dead = 0;

  // ---------- one-time LDS staging ----------
#pragma unroll
  for (int rr = 0; rr < 12; rr++) {
    int R = (rr >> 1) * HALFN + 2 * w + (rr & 1);
    const float* src = whh + (size_t)orig_row(R) * SIZEN;
    for (int k = tid * 4; k < SIZEN; k += NTHR * 4)
      *(float4*)&sm.whh[rr][k] = *(const float4*)&src[k];
  }
  if (tid < 12) sm.bhh_l[tid] = bhh[orig_row((tid >> 1) * HALFN + 2 * w + (tid & 1))];
  for (int k = tid * 4; k < HALFN; k += NTHR * 4) {
    *(float4*)&sm.wc1l[0][k] = *(const float4*)&wc1[(size_t)(2 * w) * HALFN + k];
    *(float4*)&sm.wc1l[1][k] = *(const float4*)&wc1[(size_t)(2 * w + 1) * HALFN + k];
    *(float4*)&sm.wf1l[0][k] = *(const float4*)&wf1[(size_t)(2 * w) * HALFN + k];
    *(float4*)&sm.wf1l[1][k] = *(const float4*)&wf1[(size_t)(2 * w + 1) * HALFN + k];
  }
  if (isHead) {
#pragma unroll
    for (int rr = 0; rr < 8; rr++) {
      for (int k = tid * 4; k < HALFN; k += NTHR * 4) {
        *(float4*)&sm.wc2l[rr][k] = *(const float4*)&wc2[(size_t)(w * 8 + rr) * HALFN + k];
        *(float4*)&sm.wf2l[rr][k] = *(const float4*)&wf2[(size_t)(w * 8 + rr) * HALFN + k];
      }
    }
  }
  if (tid < 12) {   // bih slice: rk -> global row R
    int rk = tid;
    int R = ((rk >= 6) ? HALFN : 0) + ((rk % 6) >> 1) * SIZEN + 2 * w + (rk & 1);
    sm.bihl[rk] = bih[R];
  }
  if (tid < 2) {    // wci/wfi slices (rows g*448 + j)
    int j = 2 * w + tid;
#pragma unroll
    for (int g = 0; g < 3; g++) {
      sm.wcil[tid][g][0] = wci[(g * HALFN + j) * 2 + 0];
      sm.wcil[tid][g][1] = wci[(g * HALFN + j) * 2 + 1];
      sm.wfil[tid][g][0] = wfi[(g * HALFN + j) * 3 + 0];
      sm.wfil[tid][g][1] = wfi[(g * HALFN + j) * 3 + 1];
      sm.wfil[tid][g][2] = wfi[(g * HALFN + j) * 3 + 2];
    }
  }
  if (tid < 64) { sm.chid[tid >> 5][tid & 31] = 0.0f; sm.fhid[tid >> 5][tid & 31] = 0.0f; }
  if (tid < 32) { sm.scvo[tid] = 128.0f * (2.0f / 255.0f) - 1.0f; sm.sfvo[tid] = -1.0f; }
  __syncthreads();

  for (int t = 0; t < TSTEPS; ++t) {
    const float* hprev = (t & 1) ? hid0 : hid1;
    float*       hcur  = (t & 1) ? hid1 : hid0;
    const int tt = t & 15;

    // ========== A: [cond prefetch] + GEMM + nf-poll + coarse GRU ==========
    {
      // 16-step cond window -> LDS (12 rows x 32 b x 16 t = 24 KB, 3 float4/thread)
      if (tt == 0) {
        for (int idx = tid; idx < 1536; idx += NTHR) {
          int rk = idx >> 7, rem = idx & 127;
          int bb = rem >> 2, part = rem & 3;
          int R = ((rk >= 6) ? HALFN : 0) + ((rk % 6) >> 1) * SIZEN + 2 * w + (rk & 1);
          float4 v = *(const float4*)&cond[(size_t)bb * CONDSTR + (size_t)R * TSTEPS + t + part * 4];
          sm.condw[rk][part * 4 + 0][bb] = v.x;
          sm.condw[rk][part * 4 + 1][bb] = v.y;
          sm.condw[rk][part * 4 + 2][bb] = v.z;
          sm.condw[rk][part * 4 + 3][bb] = v.w;
        }
      }

      float acc[12];
#pragma unroll
      for (int rr = 0; rr < 12; rr++) acc[rr] = 0.0f;
      const int k0 = ks * 56;
      const float* hcol = hprev + b;
#pragma unroll 2
      for (int k = k0; k < k0 + 56; k += 4) {
        float h0 = gload(&hcol[(k + 0) * 32]), h1v = gload(&hcol[(k + 1) * 32]);
        float h2 = gload(&hcol[(k + 2) * 32]), h3  = gload(&hcol[(k + 3) * 32]);
#pragma unroll
        for (int rr = 0; rr < 12; rr++) {
          const float4 wv = *(const float4*)&sm.whh[rr][k];
          acc[rr] = fmaf(wv.x, h0, fmaf(wv.y, h1v, fmaf(wv.z, h2, fmaf(wv.w, h3, acc[rr]))));
        }
      }
#pragma unroll
      for (int rr = 0; rr < 12; rr++) acc[rr] += __shfl_xor(acc[rr], 32);
      __syncthreads();   // red reuse fence (covers heads' F-phase reads)
      if ((tid & 32) == 0) {
        int slot = ks >> 1;
#pragma unroll
        for (int rr = 0; rr < 12; rr++) sm.red[slot][rr][b] = acc[rr];
      }
      __syncthreads();
      if (tid < 384) {
        int rr = tid >> 5, bb = tid & 31;
        float s = sm.bhh_l[rr];
#pragma unroll
        for (int kk = 0; kk < 8; kk++) s += sm.red[kk][rr][bb];
        if (rr < 6) sm.hps[rr][bb] = s;
        else        sm.hpfl[rr - 6][bb] = s;
      }
      // nf(t-1): single-address poll (heads computed it overlapped with our GEMM)
      if (t > 0) {
        pollctr(&ctr[1], 32u * (unsigned)t, &sm.pflag, dead);
        if (tid < 32) {
          u64t p = gload64(&nfp[tid]);
          unsigned nf = 0xFFFFFFFFu - (unsigned)(p & 0xFFFFFFFFull);
          sm.sfvo[tid] = (float)nf * (2.0f / 255.0f) - 1.0f;
          if (isHead && tid == w) out[32768 + (size_t)w * TSTEPS + (t - 1)] = (float)nf;
        }
      }
      __syncthreads();
      // coarse GRU for j = 2w, 2w+1 (everything LDS-local now)
      if (tid < 64) {
        int q = tid >> 5, bb = tid & 31;
        float sc = sm.scvo[bb], sf = sm.sfvo[bb];
        float ipr = sm.wcil[q][0][0] * sc + sm.wcil[q][0][1] * sf + sm.condw[0 + q][tt][bb] + sm.bihl[0 + q];
        float ipu = sm.wcil[q][1][0] * sc + sm.wcil[q][1][1] * sf + sm.condw[2 + q][tt][bb] + sm.bihl[2 + q];
        float ipe = sm.wcil[q][2][0] * sc + sm.wcil[q][2][1] * sf + sm.condw[4 + q][tt][bb] + sm.bihl[4 + q];
        float r = sigm(sm.hps[0 + q][bb] + ipr);
        float u = sigm(sm.hps[2 + q][bb] + ipu);
        float e = tanhf(fmaf(r, sm.hps[4 + q][bb], ipe));
        float hnew = u * sm.chid[q][bb] + (1.0f - u) * e;
        sm.chid[q][bb] = hnew;
        gstore(&hcur[(size_t)(2 * w + q) * 32 + bb], hnew);
      }
    }
    gridbar(flags, ++ep, dead);                       // bar1: h_c ready

    // ========== B: FC1 coarse (rows 2w,2w+1) ==========
    {
      const int k0 = ks * 28;
      float a0 = 0.0f, a1 = 0.0f;
      const float* hcc = hcur + b;
#pragma unroll
      for (int k = k0; k < k0 + 28; k += 4) {
        float h0 = gload(&hcc[(k + 0) * 32]), h1v = gload(&hcc[(k + 1) * 32]);
        float h2 = gload(&hcc[(k + 2) * 32]), h3  = gload(&hcc[(k + 3) * 32]);
        float4 v0 = *(const float4*)&sm.wc1l[0][k];
        a0 = fmaf(v0.x, h0, fmaf(v0.y, h1v, fmaf(v0.z, h2, fmaf(v0.w, h3, a0))));
        float4 v1 = *(const float4*)&sm.wc1l[1][k];
        a1 = fmaf(v1.x, h0, fmaf(v1.y, h1v, fmaf(v1.z, h2, fmaf(v1.w, h3, a1))));
      }
      a0 += __shfl_xor(a0, 32); a1 += __shfl_xor(a1, 32);
      __syncthreads();
      if ((tid & 32) == 0) { sm.red[ks >> 1][0][b] = a0; sm.red[ks >> 1][1][b] = a1; }
      if (isHead && tid == 256) gstore64(&ncp[w], 0ull);   // reset this step's pack
      __syncthreads();
      if (tid < 64) {
        int rr = tid >> 5, bb = tid & 31;
        float s = bc1[2 * w + rr];
#pragma unroll
        for (int kk = 0; kk < 8; kk++) s += sm.red[kk][rr][bb];
        gstore(&h1gc[(size_t)(2 * w + rr) * 32 + bb], fmaxf(s, 0.0f));
      }
    }
    gridbar(flags, ++ep, dead);                       // bar2: h1c ready

    // ========== C: FC2 coarse (heads) -> packed atomicMax + counter ==========
    if (isHead) {
      const int k0 = ks * 28;
      float acc[8];
#pragma unroll
      for (int rr = 0; rr < 8; rr++) acc[rr] = 0.0f;
      const float* hh = h1gc + b;
#pragma unroll
      for (int k = k0; k < k0 + 28; k += 4) {
        float h0 = gload(&hh[(k + 0) * 32]), h1v = gload(&hh[(k + 1) * 32]);
        float h2 = gload(&hh[(k + 2) * 32]), h3  = gload(&hh[(k + 3) * 32]);
#pragma unroll
        for (int rr = 0; rr < 8; rr++) {
          const float4 wv = *(const float4*)&sm.wc2l[rr][k];
          acc[rr] = fmaf(wv.x, h0, fmaf(wv.y, h1v, fmaf(wv.z, h2, fmaf(wv.w, h3, acc[rr]))));
        }
      }
#pragma unroll
      for (int rr = 0; rr < 8; rr++) acc[rr] += __shfl_xor(acc[rr], 32);
      __syncthreads();
      if ((tid & 32) == 0) {
        int slot = ks >> 1;
#pragma unroll
        for (int rr = 0; rr < 8; rr++) sm.red[slot][rr][b] = acc[rr];
      }
      __syncthreads();
      if (tid < 256) {
        int rr = tid >> 5, bb = tid & 31;
        float s = bc2[w * 8 + rr];
#pragma unroll
        for (int kk = 0; kk < 8; kk++) s += sm.red[kk][rr][bb];
        sm.logit8[rr][bb] = s;
      }
      __syncthreads();
      if (tid < 32) {
        float bv = sm.logit8[0][tid]; int bi = 0;
#pragma unroll
        for (int rr = 1; rr < 8; rr++) {
          float x = sm.logit8[rr][tid];
          if (x > bv) { bv = x; bi = rr; }
        }
        u64t pack = ((u64t)f2ord(bv) << 32) | (u64t)(0xFFFFFFFFu - (unsigned)(w * 8 + bi));
        gmax64(&ncp[tid], pack);
      }
      asm volatile("s_waitcnt vmcnt(0)" ::: "memory");
      __syncthreads();
      if (tid == 0) __hip_atomic_fetch_add(&ctr[0], 1u, __ATOMIC_RELAXED, __HIP_MEMORY_SCOPE_AGENT);
    }
    pollctr(&ctr[0], 32u * (unsigned)(t + 1), &sm.pflag, dead);   // nc ready

    // ========== D: fine GRU (all WGs, j=2w,2w+1) ==========
    {
      if (tid < 32) {
        u64t p = gload64(&ncp[tid]);
        unsigned nc = 0xFFFFFFFFu - (unsigned)(p & 0xFFFFFFFFull);
        sm.sncn[tid] = (float)nc * (2.0f / 255.0f) - 1.0f;
        if (isHead && tid == w) out[(size_t)w * TSTEPS + t] = (float)nc;
      }
      __syncthreads();
      if (tid < 64) {
        int q = tid >> 5, bb = tid & 31;
        float sc = sm.scvo[bb], sf = sm.sfvo[bb], snc = sm.sncn[bb];
        float ipr = sm.wfil[q][0][0] * sc + sm.wfil[q][0][1] * sf + sm.wfil[q][0][2] * snc
                  + sm.condw[6 + q][tt][bb] + sm.bihl[6 + q];
        float ipu = sm.wfil[q][1][0] * sc + sm.wfil[q][1][1] * sf + sm.wfil[q][1][2] * snc
                  + sm.condw[8 + q][tt][bb] + sm.bihl[8 + q];
        float ipe = sm.wfil[q][2][0] * sc + sm.wfil[q][2][1] * sf + sm.wfil[q][2][2] * snc
                  + sm.condw[10 + q][tt][bb] + sm.bihl[10 + q];
        float r = sigm(sm.hpfl[0 + q][bb] + ipr);
        float u = sigm(sm.hpfl[2 + q][bb] + ipu);
        float e = tanhf(fmaf(r, sm.hpfl[4 + q][bb], ipe));
        float hnew = u * sm.fhid[q][bb] + (1.0f - u) * e;
        sm.fhid[q][bb] = hnew;
        gstore(&hcur[(size_t)(HALFN + 2 * w + q) * 32 + bb], hnew);
      }
      __syncthreads();
      if (tid < 32) sm.scvo[tid] = sm.sncn[tid];   // commit nc(t) as old coarse sample
    }
    gridbar(flags, ++ep, dead);                       // bar3: h_f ready

    // ========== E: FC1 fine (rows 2w,2w+1) ==========
    {
      const int k0 = ks * 28;
      float a0 = 0.0f, a1 = 0.0f;
      const float* hff = hcur + HALFN * 32 + b;
#pragma unroll
      for (int k = k0; k < k0 + 28; k += 4) {
        float h0 = gload(&hff[(k + 0) * 32]), h1v = gload(&hff[(k + 1) * 32]);
        float h2 = gload(&hff[(k + 2) * 32]), h3  = gload(&hff[(k + 3) * 32]);
        float4 v0 = *(const float4*)&sm.wf1l[0][k];
        a0 = fmaf(v0.x, h0, fmaf(v0.y, h1v, fmaf(v0.z, h2, fmaf(v0.w, h3, a0))));
        float4 v1 = *(const float4*)&sm.wf1l[1][k];
        a1 = fmaf(v1.x, h0, fmaf(v1.y, h1v, fmaf(v1.z, h2, fmaf(v1.w, h3, a1))));
      }
      a0 += __shfl_xor(a0, 32); a1 += __shfl_xor(a1, 32);
      __syncthreads();
      if ((tid & 32) == 0) { sm.red[ks >> 1][0][b] = a0; sm.red[ks >> 1][1][b] = a1; }
      if (isHead && tid == 256) gstore64(&nfp[w], 0ull);   // reset this step's pack
      __syncthreads();
      if (tid < 64) {
        int rr = tid >> 5, bb = tid & 31;
        float s = bf1[2 * w + rr];
#pragma unroll
        for (int kk = 0; kk < 8; kk++) s += sm.red[kk][rr][bb];
        gstore(&h1gf[(size_t)(2 * w + rr) * 32 + bb], fmaxf(s, 0.0f));
      }
    }
    gridbar(flags, ++ep, dead);                       // bar4: h1f ready

    // ========== F: FC2 fine (heads) — overlaps next step's GEMM ==========
    if (isHead) {
      const int k0 = ks * 28;
      float acc[8];
#pragma unroll
      for (int rr = 0; rr < 8; rr++) acc[rr] = 0.0f;
      const float* hh = h1gf + b;
#pragma unroll
      for (int k = k0; k < k0 + 28; k += 4) {
        float h0 = gload(&hh[(k + 0) * 32]), h1v = gload(&hh[(k + 1) * 32]);
        float h2 = gload(&hh[(k + 2) * 32]), h3  = gload(&hh[(k + 3) * 32]);
#pragma unroll
        for (int rr = 0; rr < 8; rr++) {
          const float4 wv = *(const float4*)&sm.wf2l[rr][k];
          acc[rr] = fmaf(wv.x, h0, fmaf(wv.y, h1v, fmaf(wv.z, h2, fmaf(wv.w, h3, acc[rr]))));
        }
      }
#pragma unroll
      for (int rr = 0; rr < 8; rr++) acc[rr] += __shfl_xor(acc[rr], 32);
      __syncthreads();
      if ((tid & 32) == 0) {
        int slot = ks >> 1;
#pragma unroll
        for (int rr = 0; rr < 8; rr++) sm.red[slot][rr][b] = acc[rr];
      }
      __syncthreads();
      if (tid < 256) {
        int rr = tid >> 5, bb = tid & 31;
        float s = bf2[w * 8 + rr];
#pragma unroll
        for (int kk = 0; kk < 8; kk++) s += sm.red[kk][rr][bb];
        sm.logit8[rr][bb] = s;
      }
      __syncthreads();
      if (tid < 32) {
        float bv = sm.logit8[0][tid]; int bi = 0;
#pragma unroll
        for (int rr = 1; rr < 8; rr++) {
          float x = sm.logit8[rr][tid];
          if (x > bv) { bv = x; bi = rr; }
        }
        u64t pack = ((u64t)f2ord(bv) << 32) | (u64t)(0xFFFFFFFFu - (unsigned)(w * 8 + bi));
        gmax64(&nfp[tid], pack);
      }
      asm volatile("s_waitcnt vmcnt(0)" ::: "memory");
      __syncthreads();
      if (tid == 0) __hip_atomic_fetch_add(&ctr[1], 1u, __ATOMIC_RELAXED, __HIP_MEMORY_SCOPE_AGENT);
    }
    // no barrier: non-heads already started next GEMM; nf consumed via poll in A
  }

  // ===== epilogue: nf(1023) + final hidden =====
  pollctr(&ctr[1], 32u * (unsigned)TSTEPS, &sm.pflag, dead);
  if (tid < 32 && isHead && tid == w) {
    u64t p = gload64(&nfp[tid]);
    unsigned nf = 0xFFFFFFFFu - (unsigned)(p & 0xFFFFFFFFull);
    out[32768 + (size_t)w * TSTEPS + (TSTEPS - 1)] = (float)nf;
  }
  if (tid < 64) {
    int q = tid >> 5, bb = tid & 31;
    out[65536 + (size_t)(2 * w + q) * 32 + bb]         = sm.chid[q][bb];
    out[65536 + (size_t)(HALFN + 2 * w + q) * 32 + bb] = sm.fhid[q][bb];
  }
}

extern "C" void kernel_launch(void* const* d_in, const int* in_sizes, int n_in,
                              void* d_out, int out_size, void* d_ws, size_t ws_size,
                              hipStream_t stream) {
  const float* cond = (const float*)d_in[0];
  const float* wci  = (const float*)d_in[1];
  const float* wfi  = (const float*)d_in[2];
  const float* whh  = (const float*)d_in[3];
  const float* bih  = (const float*)d_in[4];
  const float* bhh  = (const float*)d_in[5];
  const float* wc1  = (const float*)d_in[6];
  const float* bc1  = (const float*)d_in[7];
  const float* wc2  = (const float*)d_in[8];
  const float* bc2  = (const float*)d_in[9];
  const float* wf1  = (const float*)d_in[10];
  const float* bf1  = (const float*)d_in[11];
  const float* wf2  = (const float*)d_in[12];
  const float* bf2  = (const float*)d_in[13];
  float* out = (float*)d_out;
  float* ws  = (float*)d_ws;

  hipLaunchKernelGGL(wavernn_init, dim3(64), dim3(256), 0, stream, ws);
  hipLaunchKernelGGL(wavernn_persist, dim3(NWG), dim3(NTHR), 0, stream,
                     cond, wci, wfi, whh, bih, bhh,
                     wc1, bc1, wc2, bc2, wf1, bf1, wf2, bf2, out, ws);
}